// Round 4
// baseline (424.102 us; speedup 1.0000x reference)
//
#include <hip/hip_runtime.h>

// ---------------------------------------------------------------------------
// StructuralCausalModel: 3 layers x 32 vars sequential scan, BATCH=512.
// R12: eliminate stage A algebraically. Values are maintained in the
// paW-transformed domain: valsP[v] = out_v @ paW. Then
//   X2 = gelu(pcP + embP')   with pcP = sum_v an*valsP[v],
//   embP' = emb@paW + pab    (precomputed),
//   valsP[i] = h2 @ (W3@paW) + b3@paW + NE@paW   (W3P/b3P/NE2 precomputed).
// Per step: 3 barriers (B: W1, C: W2 + pcP GEMM + snap, D: W3P -> valsP +
// lane-local fixup + gelu -> X2; raw W3 -> outp only in last 32 steps).
// Segment count 384 -> 288; stage-A GEMM and PA-resident regs gone.
// ws ~16 MB: adjb | b3P | embP | weight frags (incl W3P) | NE2 (bf16, with
// f32 W3P-temp overlaid, consumed by the swizzle pass before NE2 is written).
// ---------------------------------------------------------------------------

typedef __bf16 bf16x8 __attribute__((ext_vector_type(8)));
typedef float  f32x4  __attribute__((ext_vector_type(4)));

#define N_VARS 32
#define BTILE 4
#define NBLK 128

// ---- ws byte offsets ----
#define WS_ADJB   0            // ushort[32*64]  (4 KB)
#define WS_B3P    4096         // float [32*256] (32 KB)
#define WS_EMBP   36864        // float [32*256] (32 KB)
#define WS_WSB    69632        // bf16 weight-fragment base
// element offsets within wsb (ushort elements)
#define ELOFF_PA  0
#define ELOFF_W1  65536
#define ELOFF_W2  1114112
#define ELOFF_W3  1638400
#define ELOFF_W3P 2686976
// wsb total el = 3735552 -> 7471104 B; ends at 69632+7471104 = 7540736
#define WS_NE2    7540736      // ushort[512*32*256] = 8 MB; f32 W3P temp overlays
// total ws = 15929344 B (~15.9 MB)

// LDS row strides (ushorts).
#define XSTR 272
#define HSTR 144
#define VSTR 40    // valsP col stride (80 B): b128 frag reads 16B-aligned

__device__ __forceinline__ unsigned short f2b(float f) {
    unsigned u = __float_as_uint(f);
    u += 0x7FFFu + ((u >> 16) & 1u);
    return (unsigned short)(u >> 16);
}

__device__ __forceinline__ float b2f(unsigned short u) {
    return __uint_as_float(((unsigned)u) << 16);
}

// lgkm-only barrier: LDS ordering enforced, global loads stay in flight.
__device__ __forceinline__ void bar_lds() {
    asm volatile("s_waitcnt lgkmcnt(0)\n\ts_barrier" ::: "memory");
}

// erf via Abramowitz-Stegun 7.1.25, 3 terms (|err| <= 2.5e-5)
__device__ __forceinline__ float gelu_e(float x) {
    float z  = x * 0.7071067811865476f;
    float az = fabsf(z);
    float t  = __builtin_amdgcn_rcpf(1.0f + 0.47047f * az);
    float p  = t * (0.3480242f + t * (-0.0958798f + t * 0.7478556f));
    float e  = 1.0f - p * __expf(-z * z);
    float er = (z < 0.0f) ? -e : e;
    return 0.5f * x * (1.0f + er);
}

// Extract element q (q = lane>>4, runtime) via compile-time-indexed selects.
__device__ __forceinline__ float pickq(f32x4 v, int q) {
    float lo = (q & 1) ? v[1] : v[0];
    float hi = (q & 1) ? v[3] : v[2];
    return (q & 2) ? hi : lo;
}
__device__ __forceinline__ float pick4(float x0, float x1, float x2, float x3, int q) {
    float lo = (q & 1) ? x1 : x0;
    float hi = (q & 1) ? x3 : x2;
    return (q & 2) ? hi : lo;
}

#define MFMA16(a, b, c) __builtin_amdgcn_mfma_f32_16x16x32_bf16(a, b, c, 0, 0, 0)

// ---------------------------------------------------------------------------
// prep_lin (576 blocks x 256): fused-weight precomputes (all f32 exact).
//  [0,512):  W3P_tmp[v][m][d] = sum_n W3[v][m][n]*paW[n][d]   (8 m-rows/blk)
//  [512,544): b3P[v][d] = sum_n b3[v][n]*paW[n][d]
//  [544,576): embP[v][d] = sum_n emb[v][n]*paW[n][d] + pab[d]
// ---------------------------------------------------------------------------
__global__ void prep_lin(const float* __restrict__ paW, const float* __restrict__ mW3,
                         const float* __restrict__ mb3, const float* __restrict__ emb,
                         const float* __restrict__ pab,
                         float* __restrict__ tmpf, float* __restrict__ b3P,
                         float* __restrict__ embP) {
    const int b = blockIdx.x, d = threadIdx.x;
    if (b < 512) {
        const int v = b >> 4, mg = (b & 15) * 8;
        const float* w3r = mW3 + (size_t)(v * 128 + mg) * 256;
        float acc[8];
        #pragma unroll
        for (int r = 0; r < 8; r++) acc[r] = 0.f;
        for (int n = 0; n < 256; n++) {
            float pa = paW[n * 256 + d];
            #pragma unroll
            for (int r = 0; r < 8; r++) acc[r] += w3r[r * 256 + n] * pa;
        }
        #pragma unroll
        for (int r = 0; r < 8; r++)
            tmpf[(size_t)(v * 128 + mg + r) * 256 + d] = acc[r];
    } else if (b < 544) {
        const int v = b - 512;
        float a = 0.f;
        for (int n = 0; n < 256; n++) a += mb3[v * 256 + n] * paW[n * 256 + d];
        b3P[v * 256 + d] = a;
    } else {
        const int v = b - 544;
        float a = pab[d];
        for (int n = 0; n < 256; n++) a += emb[v * 256 + n] * paW[n * 256 + d];
        embP[v * 256 + d] = a;
    }
}

// ---------------------------------------------------------------------------
// prep_all (1673 blocks x 256): [0,648) weight swizzle via LDS tile
// (PA, W1, W2, W3, W3P-from-tmp); 648 adjacency (bf16 hi/lo);
// [649,1673) noise encoder NE -> outp.
// B-frag (16x16x32): lane l, elem j -> k = ks*32+(l>>4)*8+j, n = nt*16+(l&15)
// ---------------------------------------------------------------------------
__global__ void prep_all(const float* __restrict__ paW, const float* __restrict__ mW1,
                         const float* __restrict__ mW2, const float* __restrict__ mW3,
                         const float* __restrict__ edge, unsigned short* __restrict__ wsb,
                         unsigned short* __restrict__ adjb,
                         const float* __restrict__ noise, const float* __restrict__ neW,
                         const float* __restrict__ neb, float* __restrict__ outp,
                         const float* __restrict__ tmpf) {
    __shared__ unsigned short tile[32 * 256];
    const int c = blockIdx.x, tid = threadIdx.x;
    if (c < 648) {
        const float* src; unsigned short* dst; int N, KS, ks;
        if (c < 8)        { src = paW;                     dst = wsb + ELOFF_PA;              N = 256; KS = 8; ks = c; }
        else if (c < 264) { int v = (c - 8) >> 3;   ks = (c - 8) & 7;
                            src = mW1 + v * 32768;         dst = wsb + ELOFF_W1 + v * 32768;  N = 128; KS = 8; }
        else if (c < 392) { int v = (c - 264) >> 2; ks = (c - 264) & 3;
                            src = mW2 + v * 16384;         dst = wsb + ELOFF_W2 + v * 16384;  N = 128; KS = 4; }
        else if (c < 520) { int v = (c - 392) >> 2; ks = (c - 392) & 3;
                            src = mW3 + v * 32768;         dst = wsb + ELOFF_W3 + v * 32768;  N = 256; KS = 4; }
        else              { int v = (c - 520) >> 2; ks = (c - 520) & 3;
                            src = tmpf + v * 32768;        dst = wsb + ELOFF_W3P + v * 32768; N = 256; KS = 4; }
        const int kb = ks * 32, nsh = (N == 256) ? 8 : 7;
        for (int t = tid; t < 32 * N; t += 256) {
            int r = t >> nsh, col = t & (N - 1);
            tile[r * N + col] = f2b(src[(kb + r) * N + col]);   // coalesced in col
        }
        __syncthreads();
        const int nout = (N >> 4) * 64;
        for (int o = tid; o < nout; o += 256) {
            int nt = o >> 6, lane = o & 63;
            int n = nt * 16 + (lane & 15), k0 = (lane >> 4) << 3;
            unsigned e[8];
            #pragma unroll
            for (int j = 0; j < 8; j++) e[j] = tile[(k0 + j) * N + n];
            uint4 pk;
            pk.x = e[0] | (e[1] << 16); pk.y = e[2] | (e[3] << 16);
            pk.z = e[4] | (e[5] << 16); pk.w = e[6] | (e[7] << 16);
            *(uint4*)(dst + ((nt * KS + ks) * 64 + lane) * 8) = pk;   // coalesced
        }
    } else if (c == 648) {
        for (int t = tid; t < 1024; t += 256) {
            int v = t >> 5, ci = t & 31;
            float x = edge[t];
            float m = (v == ci) ? 0.0f : x;   // diag logit masked -> adj diag = 0.5
            float a = __builtin_amdgcn_rcpf(1.0f + __expf(-2.0f * m));
            unsigned short hi = f2b(a);
            float rem = a - b2f(hi);
            adjb[ci * 64 + v]      = hi;        // row ci: parents-of-ci weights
            adjb[ci * 64 + 32 + v] = f2b(rem);  // low part (an ~ 16-bit mantissa)
        }
    } else {
        int sb = c - 649;                     // 1024 sub-blocks: 32 vars x 32 groups
        int i = sb >> 5, g = sb & 31, d = tid;
        float w[64];
        #pragma unroll
        for (int k = 0; k < 64; k++) w[k] = neW[(i * 64 + k) * 256 + d];
        float bias = neb[i * 256 + d];
        for (int bb = 0; bb < 16; bb++) {
            int b = g * 16 + bb;
            const float* nr = noise + (b * 32 + i) * 64;
            float a0 = bias, a1 = 0.f, a2 = 0.f, a3 = 0.f;
            #pragma unroll
            for (int k = 0; k < 16; k++) {      // 4 independent fma chains
                a0 += nr[4 * k + 0] * w[4 * k + 0];
                a1 += nr[4 * k + 1] * w[4 * k + 1];
                a2 += nr[4 * k + 2] * w[4 * k + 2];
                a3 += nr[4 * k + 3] * w[4 * k + 3];
            }
            outp[(b * 32 + i) * 256 + d] = gelu_e((a0 + a1) + (a2 + a3));
        }
    }
}

// ---------------------------------------------------------------------------
// prep_ne2 (256 blocks x 256): NE2 = NE @ paW via MFMA, using the PA frags
// already swizzled into ws. Rows = 16384 (b*32+i); 1024 row-tiles of 16,
// one per wave. A-frag: lane l row = l&15, k = (l>>4)*8+j.
// ---------------------------------------------------------------------------
__global__ void prep_ne2(const float* __restrict__ nep, const __bf16* __restrict__ wsbf,
                         unsigned short* __restrict__ ne2) {
    const int tid = threadIdx.x;
    const int wid = tid >> 6, lane = tid & 63, l15 = lane & 15, q = lane >> 4;
    const int gt = blockIdx.x * 4 + wid;          // [0,1024)
    const int rowbase = gt * 16;
    bf16x8 afr[8];
    #pragma unroll
    for (int ks = 0; ks < 8; ks++) {
        const float* s = nep + (size_t)(rowbase + l15) * 256 + ks * 32 + q * 8;
        float4 x0 = *(const float4*)s;
        float4 x1 = *(const float4*)(s + 4);
        uint4 pk;
        pk.x = (unsigned)f2b(x0.x) | ((unsigned)f2b(x0.y) << 16);
        pk.y = (unsigned)f2b(x0.z) | ((unsigned)f2b(x0.w) << 16);
        pk.z = (unsigned)f2b(x1.x) | ((unsigned)f2b(x1.y) << 16);
        pk.w = (unsigned)f2b(x1.z) | ((unsigned)f2b(x1.w) << 16);
        afr[ks] = __builtin_bit_cast(bf16x8, pk);
    }
    #pragma unroll 4
    for (int nt = 0; nt < 16; nt++) {
        f32x4 e4 = {0, 0, 0, 0}, o4 = {0, 0, 0, 0};
        #pragma unroll
        for (int ks = 0; ks < 8; ks += 2) {
            bf16x8 b0 = *(const bf16x8*)(wsbf + ELOFF_PA + ((nt * 8 + ks) * 64 + lane) * 8);
            bf16x8 b1 = *(const bf16x8*)(wsbf + ELOFF_PA + ((nt * 8 + ks + 1) * 64 + lane) * 8);
            e4 = MFMA16(afr[ks], b0, e4);
            o4 = MFMA16(afr[ks + 1], b1, o4);
        }
        f32x4 a = e4 + o4;
        #pragma unroll
        for (int r = 0; r < 4; r++)
            ne2[(size_t)(rowbase + 4 * q + r) * 256 + nt * 16 + l15] = f2b(a[r]);
    }
}

// ---------------------------------------------------------------------------
// Main: 128 blocks x 512 threads. 3 barriers/step.
// B: W1 GEMM -> Hs1.  C: W2 GEMM -> Hs2; pcP GEMM (pre-update valsP); snap.
// D: W3P GEMM + b3P + NE2 -> valsP[i]; lane-local fixup + gelu -> X2;
//    last layer only: raw W3 GEMM + b3 + NE -> outp.
// ---------------------------------------------------------------------------
__global__ __launch_bounds__(512) void
scm_main(const float* __restrict__ embP, const float* __restrict__ b3Pp,
         const float* __restrict__ mb1, const float* __restrict__ mb2,
         const float* __restrict__ mb3, const unsigned short* __restrict__ adjb,
         const __bf16* __restrict__ wsbf, const unsigned short* __restrict__ ne2,
         float* __restrict__ outp) {
    __shared__ unsigned short valsP[1024 * VSTR];  // [col=b*256+d][var] 80 KB
    __shared__ unsigned short X2[4 * XSTR];
    __shared__ unsigned short Hs1[4 * HSTR];
    __shared__ unsigned short Hs2[4 * HSTR];

    const int tid = threadIdx.x, blk = blockIdx.x;

    {   // zero valsP (1024*40 ushorts = 5120 uint4)
        uint4 z; z.x = z.y = z.z = z.w = 0;
        for (int k = tid; k < 5120; k += 512) ((uint4*)valsP)[k] = z;
    }

    const int wid = tid >> 6, lane = tid & 63, l15 = lane & 15, q = lane >> 4;
    const int l3 = l15 & 3;                 // A-frag row (BTILE=4; rows alias)
    const int nW = wid * 16 + l15;
    const int n0 = nW, n1 = nW + 128;

    // seed X2 for step 0: valsP = 0 -> pcP = 0 -> X2 = gelu(embP'_0)
    X2[q * XSTR + n0] = f2b(gelu_e(embP[n0]));
    X2[q * XSTR + n1] = f2b(gelu_e(embP[n1]));
    bar_lds();

    for (int s = 0; s < 3 * N_VARS; s++) {
        const int i = s & 31, ni = (s + 1) & 31;
        const bool last = s >= 64;

        // ---- step-top prefetch: all per-var step-i globals ----
        float bi1 = mb1[i * 128 + nW];
        float bi2 = mb2[i * 128 + nW];
        bf16x8 w1f[8];
        #pragma unroll
        for (int ks = 0; ks < 8; ks++)
            w1f[ks] = *(const bf16x8*)(wsbf + ELOFF_W1 + (size_t)i * 32768 +
                                       ((wid * 8 + ks) * 64 + lane) * 8);
        bf16x8 w2f[4], wPf0[4], wPf1[4];
        #pragma unroll
        for (int ks = 0; ks < 4; ks++) {
            w2f[ks]  = *(const bf16x8*)(wsbf + ELOFF_W2 + (size_t)i * 16384 +
                                        ((wid * 4 + ks) * 64 + lane) * 8);
            wPf0[ks] = *(const bf16x8*)(wsbf + ELOFF_W3P + (size_t)i * 32768 +
                                        ((wid * 4 + ks) * 64 + lane) * 8);
            wPf1[ks] = *(const bf16x8*)(wsbf + ELOFF_W3P + (size_t)i * 32768 +
                                        (((wid + 8) * 4 + ks) * 64 + lane) * 8);
        }
        // transformed-domain per-step scalars (row q, cols n0/n1)
        const size_t nrow = ((size_t)(blk * BTILE + q) * 32 + i) * 256;
        const float ne2_0 = b2f(ne2[nrow + n0]);
        const float ne2_1 = b2f(ne2[nrow + n1]);
        const float b3P0 = b3Pp[i * 256 + n0];
        const float b3P1 = b3Pp[i * 256 + n1];
        const float eP0 = embP[ni * 256 + n0];
        const float eP1 = embP[ni * 256 + n1];
        // adjacency A-frags (hi/lo) for next-var pc GEMM + scalar an[i]
        bf16x8 anh = *(const bf16x8*)(adjb + ni * 64 + q * 8);
        bf16x8 anl = *(const bf16x8*)(adjb + ni * 64 + 32 + q * 8);
        const float ani = b2f(adjb[ni * 64 + i]) + b2f(adjb[ni * 64 + 32 + i]);
        // last-layer-only: raw W3 frags, b3, NE
        bf16x8 w3f0[4], w3f1[4];
        float b3a = 0.f, b3b = 0.f, neq0 = 0.f, neq1 = 0.f;
        if (last) {
            #pragma unroll
            for (int ks = 0; ks < 4; ks++) {
                w3f0[ks] = *(const bf16x8*)(wsbf + ELOFF_W3 + (size_t)i * 32768 +
                                            ((wid * 4 + ks) * 64 + lane) * 8);
                w3f1[ks] = *(const bf16x8*)(wsbf + ELOFF_W3 + (size_t)i * 32768 +
                                            (((wid + 8) * 4 + ks) * 64 + lane) * 8);
            }
            b3a = mb3[i * 256 + n0];
            b3b = mb3[i * 256 + n1];
            neq0 = outp[nrow + n0];
            neq1 = outp[nrow + n1];
        }

        // ==== B: W1 GEMM on X2 -> Hs1 ====
        {
            f32x4 aa = {0, 0, 0, 0}, ab = {0, 0, 0, 0};
            f32x4 ac = {0, 0, 0, 0}, ad = {0, 0, 0, 0};
            #pragma unroll
            for (int ks = 0; ks < 8; ks += 4) {
                bf16x8 af0 = *(const bf16x8*)(X2 + l3 * XSTR + ks * 32 + q * 8);
                bf16x8 af1 = *(const bf16x8*)(X2 + l3 * XSTR + (ks + 1) * 32 + q * 8);
                bf16x8 af2 = *(const bf16x8*)(X2 + l3 * XSTR + (ks + 2) * 32 + q * 8);
                bf16x8 af3 = *(const bf16x8*)(X2 + l3 * XSTR + (ks + 3) * 32 + q * 8);
                aa = MFMA16(af0, w1f[ks], aa);
                ab = MFMA16(af1, w1f[ks + 1], ab);
                ac = MFMA16(af2, w1f[ks + 2], ac);
                ad = MFMA16(af3, w1f[ks + 3], ad);
            }
            float sb = (pickq(aa, q) + pickq(ab, q)) +
                       (pickq(ac, q) + pickq(ad, q)) + bi1;
            Hs1[q * HSTR + nW] = f2b(gelu_e(sb));
        }
        bar_lds();

        // ==== C: W2 GEMM; pcP GEMM (pre-update valsP, hi/lo an); snap old ====
        f32x4 P0[4], P1[4];
        float oP0, oP1;
        {
            f32x4 ca = {0, 0, 0, 0}, cb = {0, 0, 0, 0};
            #pragma unroll
            for (int ks = 0; ks < 4; ks += 2) {
                bf16x8 af0 = *(const bf16x8*)(Hs1 + l3 * HSTR + ks * 32 + q * 8);
                bf16x8 af1 = *(const bf16x8*)(Hs1 + l3 * HSTR + (ks + 1) * 32 + q * 8);
                ca = MFMA16(af0, w2f[ks], ca);
                cb = MFMA16(af1, w2f[ks + 1], cb);
            }
            // pcP: one K=32 tile per (b=t, col set). B-frag = 8 contiguous vars.
            #pragma unroll
            for (int t = 0; t < 4; t++) {
                bf16x8 vf0 = *(const bf16x8*)(valsP + (t * 256 + n0) * VSTR + q * 8);
                bf16x8 vf1 = *(const bf16x8*)(valsP + (t * 256 + n1) * VSTR + q * 8);
                f32x4 z = {0, 0, 0, 0};
                P0[t] = MFMA16(anl, vf0, MFMA16(anh, vf0, z));
                P1[t] = MFMA16(anl, vf1, MFMA16(anh, vf1, z));
            }
            oP0 = b2f(valsP[(q * 256 + n0) * VSTR + i]);
            oP1 = b2f(valsP[(q * 256 + n1) * VSTR + i]);
            float scv = pickq(ca, q) + pickq(cb, q) + bi2;
            Hs2[q * HSTR + nW] = f2b(gelu_e(scv));
        }
        bar_lds();

        // ==== D: W3P GEMM -> valsP[i]; fixup + gelu -> X2; (last: W3 -> outp) ====
        {
            f32x4 c0a = {0, 0, 0, 0}, c0b = {0, 0, 0, 0};
            f32x4 c1a = {0, 0, 0, 0}, c1b = {0, 0, 0, 0};
            #pragma unroll
            for (int ks = 0; ks < 4; ks += 2) {
                bf16x8 af0 = *(const bf16x8*)(Hs2 + l3 * HSTR + ks * 32 + q * 8);
                bf16x8 af1 = *(const bf16x8*)(Hs2 + l3 * HSTR + (ks + 1) * 32 + q * 8);
                c0a = MFMA16(af0, wPf0[ks], c0a);
                c1a = MFMA16(af0, wPf1[ks], c1a);
                c0b = MFMA16(af1, wPf0[ks + 1], c0b);
                c1b = MFMA16(af1, wPf1[ks + 1], c1b);
            }
            float nP0 = pickq(c0a, q) + pickq(c0b, q) + b3P0 + ne2_0;
            float nP1 = pickq(c1a, q) + pickq(c1b, q) + b3P1 + ne2_1;
            unsigned short ur0 = f2b(nP0), ur1 = f2b(nP1);
            valsP[(q * 256 + n0) * VSTR + i] = ur0;
            valsP[(q * 256 + n1) * VSTR + i] = ur1;
            // lane-local fixup in transformed domain -> X2 for step ni
            float pc0 = pick4(P0[0][0], P0[1][0], P0[2][0], P0[3][0], q);
            float pc1 = pick4(P1[0][0], P1[1][0], P1[2][0], P1[3][0], q);
            float x0 = pc0 + ani * (b2f(ur0) - oP0) + eP0;
            float x1 = pc1 + ani * (b2f(ur1) - oP1) + eP1;
            X2[q * XSTR + n0] = f2b(gelu_e(x0));
            X2[q * XSTR + n1] = f2b(gelu_e(x1));
            if (last) {
                f32x4 d0a = {0, 0, 0, 0}, d0b = {0, 0, 0, 0};
                f32x4 d1a = {0, 0, 0, 0}, d1b = {0, 0, 0, 0};
                #pragma unroll
                for (int ks = 0; ks < 4; ks += 2) {
                    bf16x8 af0 = *(const bf16x8*)(Hs2 + l3 * HSTR + ks * 32 + q * 8);
                    bf16x8 af1 = *(const bf16x8*)(Hs2 + l3 * HSTR + (ks + 1) * 32 + q * 8);
                    d0a = MFMA16(af0, w3f0[ks], d0a);
                    d1a = MFMA16(af0, w3f1[ks], d1a);
                    d0b = MFMA16(af1, w3f0[ks + 1], d0b);
                    d1b = MFMA16(af1, w3f1[ks + 1], d1b);
                }
                outp[nrow + n0] = pickq(d0a, q) + pickq(d0b, q) + b3a + neq0;
                outp[nrow + n1] = pickq(d1a, q) + pickq(d1b, q) + b3b + neq1;
            }
        }
        bar_lds();
    }
}

extern "C" void kernel_launch(void* const* d_in, const int* in_sizes, int n_in,
                              void* d_out, int out_size, void* d_ws, size_t ws_size,
                              hipStream_t stream) {
    (void)in_sizes; (void)n_in; (void)out_size; (void)ws_size;
    const float* noise = (const float*)d_in[0];
    const float* edge  = (const float*)d_in[1];
    const float* emb   = (const float*)d_in[2];
    const float* paW   = (const float*)d_in[3];
    const float* pab   = (const float*)d_in[4];
    const float* mW1   = (const float*)d_in[5];
    const float* mb1   = (const float*)d_in[6];
    const float* mW2   = (const float*)d_in[7];
    const float* mb2   = (const float*)d_in[8];
    const float* mW3   = (const float*)d_in[9];
    const float* mb3   = (const float*)d_in[10];
    const float* neW   = (const float*)d_in[11];
    const float* neb   = (const float*)d_in[12];
    float* outp = (float*)d_out;

    unsigned short* adjb = (unsigned short*)((char*)d_ws + WS_ADJB);
    float* b3P  = (float*)((char*)d_ws + WS_B3P);
    float* embP = (float*)((char*)d_ws + WS_EMBP);
    unsigned short* wsb  = (unsigned short*)((char*)d_ws + WS_WSB);
    float* tmpf = (float*)((char*)d_ws + WS_NE2);             // overlay (consumed
    unsigned short* ne2u = (unsigned short*)((char*)d_ws + WS_NE2); // before NE2 write)

    prep_lin<<<576, 256, 0, stream>>>(paW, mW3, mb3, emb, pab, tmpf, b3P, embP);
    prep_all<<<1673, 256, 0, stream>>>(paW, mW1, mW2, mW3, edge, wsb, adjb,
                                       noise, neW, neb, outp, tmpf);
    prep_ne2<<<256, 256, 0, stream>>>(outp, (const __bf16*)wsb, ne2u);
    scm_main<<<NBLK, 512, 0, stream>>>(embP, b3P, mb1, mb2, mb3, adjb,
                                       (const __bf16*)wsb, ne2u, outp);
}